// Round 20
// baseline (64.326 us; speedup 1.0000x reference)
//
#include <hip/hip_runtime.h>
#include <hip/hip_bf16.h>
#include <hip/hip_cooperative_groups.h>
#include <cstdint>
#include <cstddef>

namespace cg = cooperative_groups;

#define NNODES 4096
#define NHEADS 4
#define NBR_STRIDE 128
#define NBLK 2048

typedef __attribute__((ext_vector_type(8))) short bf16x8v;
typedef __attribute__((ext_vector_type(4))) float f32x4;

__device__ inline unsigned short bf16_rn(float f) {
    unsigned int u = __float_as_uint(f);
    u += 0x7FFFu + ((u >> 16) & 1u);
    return (unsigned short)(u >> 16);
}
__device__ inline float bf16_f32(unsigned short s) {
    return __uint_as_float(((unsigned int)s) << 16);
}

// ---------------------------------------------------------------------------
// nbr v3 body: 4 waves scan quarter-rows into per-wave LDS slots; barrier;
// prefix over 4 counts; coalesced 128-int write. Trailing barrier for reuse.
// ---------------------------------------------------------------------------
__device__ inline void build_nbr_body3(
    char* arena,
    const float* __restrict__ adj, int* __restrict__ nbr, int* __restrict__ deg,
    int row) {
    int* slots = (int*)arena;            // [4][128]
    int* cnts  = (int*)(arena + 2048);   // [4]
    int wave = threadIdx.x >> 6;
    int lane = threadIdx.x & 63;
    const float4* arow =
        reinterpret_cast<const float4*>(adj + (size_t)row * NNODES) + wave * 256;
    float4 v[4];
    #pragma unroll
    for (int it = 0; it < 4; ++it) v[it] = arow[it * 64 + lane];
    unsigned long long lt = (1ull << lane) - 1ull;
    int* slot = slots + wave * 128;
    int base = 0;
    #pragma unroll
    for (int it = 0; it < 4; ++it) {
        bool b0 = v[it].x > 0.f, b1 = v[it].y > 0.f, b2 = v[it].z > 0.f, b3 = v[it].w > 0.f;
        unsigned long long m0 = __ballot(b0);
        unsigned long long m1 = __ballot(b1);
        unsigned long long m2 = __ballot(b2);
        unsigned long long m3 = __ballot(b3);
        int pre = __popcll(m0 & lt) + __popcll(m1 & lt) +
                  __popcll(m2 & lt) + __popcll(m3 & lt);
        int pos = base + pre;
        int colb = wave * 1024 + it * 256 + lane * 4;
        if (b0) { if (pos < NBR_STRIDE) slot[pos] = colb;     pos++; }
        if (b1) { if (pos < NBR_STRIDE) slot[pos] = colb + 1; pos++; }
        if (b2) { if (pos < NBR_STRIDE) slot[pos] = colb + 2; pos++; }
        if (b3) { if (pos < NBR_STRIDE) slot[pos] = colb + 3; pos++; }
        base += __popcll(m0) + __popcll(m1) + __popcll(m2) + __popcll(m3);
    }
    if (lane == 0) cnts[wave] = base < NBR_STRIDE ? base : NBR_STRIDE;
    __syncthreads();
    int c0 = cnts[0], c1 = cnts[1], c2 = cnts[2];
    int tot = c0 + c1 + c2 + cnts[3];
    if (tot > NBR_STRIDE) tot = NBR_STRIDE;
    int t = threadIdx.x;
    if (t < tot) {
        int val;
        if (t < c0)                val = slots[t];
        else if (t < c0 + c1)      val = slots[128 + t - c0];
        else if (t < c0 + c1 + c2) val = slots[256 + t - c0 - c1];
        else                       val = slots[384 + t - c0 - c1 - c2];
        nbr[row * NBR_STRIDE + t] = val;
    }
    if (t == 0) deg[row] = tot;
    __syncthreads();
}

// ---------------------------------------------------------------------------
// pack body: both layers' W -> transposed hi/lo bf16
// ---------------------------------------------------------------------------
__device__ inline void pack_body(
    const float* __restrict__ W1, const float* __restrict__ W2,
    unsigned short* __restrict__ B1h, unsigned short* __restrict__ B1l,
    unsigned short* __restrict__ B2h, unsigned short* __restrict__ B2l,
    int t) {
    if (t < 256 * 512) {
        int n = t >> 9, k = t & 511;
        int h = n >> 6, o = n & 63;
        float v = W1[((size_t)h * 512 + k) * 64 + o];
        unsigned short hi = bf16_rn(v);
        B1h[t] = hi;
        B1l[t] = bf16_rn(v - bf16_f32(hi));
    } else {
        int u = t - 256 * 512;
        if (u < 128 * 256) {
            int n = u >> 8, k = u & 255;
            int h = n >> 5, o = n & 31;
            float v = W2[((size_t)h * 256 + k) * 32 + o];
            unsigned short hi = bf16_rn(v);
            B2h[u] = hi;
            B2l[u] = bf16_rn(v - bf16_f32(hi));
        }
    }
}

// ---------------------------------------------------------------------------
// gemm body, software-pipelined (r19 verbatim).
// ---------------------------------------------------------------------------
template <int K, int N, int FO, int BK, bool ASPLIT>
__device__ inline void gemm_body(
    char* arena,
    const float* __restrict__ A,
    const unsigned short* __restrict__ Ah, const unsigned short* __restrict__ Al,
    const unsigned short* __restrict__ Bh, const unsigned short* __restrict__ Bl,
    const float* __restrict__ a, float* __restrict__ C,
    float* __restrict__ asrc, float* __restrict__ adst,
    int bx, int by) {
    constexpr int BM = 32, BN = 64, LP = BK + 8;
    constexpr int ALD = BM * LP * 2;
    constexpr int BLD = BN * LP * 2;
    typedef unsigned short (*lds_t)[LP];
    lds_t Alh = (lds_t)(arena);
    lds_t All = (lds_t)(arena + ALD);
    lds_t Blh = (lds_t)(arena + 2 * ALD);
    lds_t Bll = (lds_t)(arena + 2 * ALD + BLD);
    float* reds = (float*)(arena + 2 * ALD + 2 * BLD);          // [2][32]
    float* redd = (float*)(arena + 2 * ALD + 2 * BLD + 256);    // [2][32]
    int tid = threadIdx.x;
    int wave = tid >> 6, lane = tid & 63;
    int rowBase = bx * BM;
    int colBase = by * BN;
    int wr = wave >> 1, wc = wave & 1;
    int lr = lane & 15, lk = lane >> 4;
    f32x4 acc0 = {0.f, 0.f, 0.f, 0.f};
    f32x4 acc1 = {0.f, 0.f, 0.f, 0.f};

    if constexpr (BK == 32) {
        int ar = tid >> 3, acf = (tid & 7) * 4;     // A: 32x32
        int br = tid >> 2, bc = (tid & 3) * 8;      // B: 64x32
        uint4 bh = *reinterpret_cast<const uint4*>(&Bh[(size_t)(colBase + br) * K + bc]);
        uint4 bl = *reinterpret_cast<const uint4*>(&Bl[(size_t)(colBase + br) * K + bc]);
        uint2 avh, avl; float4 a0;
        if constexpr (ASPLIT) {
            avh = *reinterpret_cast<const uint2*>(&Ah[(size_t)(rowBase + ar) * K + acf]);
            avl = *reinterpret_cast<const uint2*>(&Al[(size_t)(rowBase + ar) * K + acf]);
        } else {
            a0 = *reinterpret_cast<const float4*>(&A[(size_t)(rowBase + ar) * K + acf]);
        }
        for (int k0 = 0; k0 < K; k0 += BK) {
            __syncthreads();
            if constexpr (ASPLIT) {
                *reinterpret_cast<uint2*>(&Alh[ar][acf]) = avh;
                *reinterpret_cast<uint2*>(&All[ar][acf]) = avl;
            } else {
                ushort4 h4, l4;
                h4.x = bf16_rn(a0.x); l4.x = bf16_rn(a0.x - bf16_f32(h4.x));
                h4.y = bf16_rn(a0.y); l4.y = bf16_rn(a0.y - bf16_f32(h4.y));
                h4.z = bf16_rn(a0.z); l4.z = bf16_rn(a0.z - bf16_f32(h4.z));
                h4.w = bf16_rn(a0.w); l4.w = bf16_rn(a0.w - bf16_f32(h4.w));
                *reinterpret_cast<ushort4*>(&Alh[ar][acf]) = h4;
                *reinterpret_cast<ushort4*>(&All[ar][acf]) = l4;
            }
            *reinterpret_cast<uint4*>(&Blh[br][bc]) = bh;
            *reinterpret_cast<uint4*>(&Bll[br][bc]) = bl;
            __syncthreads();
            int kn = k0 + BK;
            if (kn < K) {
                bh = *reinterpret_cast<const uint4*>(&Bh[(size_t)(colBase + br) * K + kn + bc]);
                bl = *reinterpret_cast<const uint4*>(&Bl[(size_t)(colBase + br) * K + kn + bc]);
                if constexpr (ASPLIT) {
                    avh = *reinterpret_cast<const uint2*>(&Ah[(size_t)(rowBase + ar) * K + kn + acf]);
                    avl = *reinterpret_cast<const uint2*>(&Al[(size_t)(rowBase + ar) * K + kn + acf]);
                } else {
                    a0 = *reinterpret_cast<const float4*>(&A[(size_t)(rowBase + ar) * K + kn + acf]);
                }
            }
            int kb = lk * 8;
            bf16x8v ah = *reinterpret_cast<const bf16x8v*>(&Alh[wr * 16 + lr][kb]);
            bf16x8v al = *reinterpret_cast<const bf16x8v*>(&All[wr * 16 + lr][kb]);
            bf16x8v b0h = *reinterpret_cast<const bf16x8v*>(&Blh[wc * 32 + lr][kb]);
            bf16x8v b0l = *reinterpret_cast<const bf16x8v*>(&Bll[wc * 32 + lr][kb]);
            bf16x8v b1h = *reinterpret_cast<const bf16x8v*>(&Blh[wc * 32 + 16 + lr][kb]);
            bf16x8v b1l = *reinterpret_cast<const bf16x8v*>(&Bll[wc * 32 + 16 + lr][kb]);
            acc0 = __builtin_amdgcn_mfma_f32_16x16x32_bf16(ah, b0h, acc0, 0, 0, 0);
            acc0 = __builtin_amdgcn_mfma_f32_16x16x32_bf16(ah, b0l, acc0, 0, 0, 0);
            acc0 = __builtin_amdgcn_mfma_f32_16x16x32_bf16(al, b0h, acc0, 0, 0, 0);
            acc1 = __builtin_amdgcn_mfma_f32_16x16x32_bf16(ah, b1h, acc1, 0, 0, 0);
            acc1 = __builtin_amdgcn_mfma_f32_16x16x32_bf16(ah, b1l, acc1, 0, 0, 0);
            acc1 = __builtin_amdgcn_mfma_f32_16x16x32_bf16(al, b1h, acc1, 0, 0, 0);
        }
    } else {   // BK == 64
        int ar = tid >> 3, ac = (tid & 7) * 8;
        uint4 bh0 = *reinterpret_cast<const uint4*>(&Bh[(size_t)(colBase + ar) * K + ac]);
        uint4 bl0 = *reinterpret_cast<const uint4*>(&Bl[(size_t)(colBase + ar) * K + ac]);
        uint4 bh1 = *reinterpret_cast<const uint4*>(&Bh[(size_t)(colBase + 32 + ar) * K + ac]);
        uint4 bl1 = *reinterpret_cast<const uint4*>(&Bl[(size_t)(colBase + 32 + ar) * K + ac]);
        uint4 avh, avl; float4 a0, a1;
        if constexpr (ASPLIT) {
            avh = *reinterpret_cast<const uint4*>(&Ah[(size_t)(rowBase + ar) * K + ac]);
            avl = *reinterpret_cast<const uint4*>(&Al[(size_t)(rowBase + ar) * K + ac]);
        } else {
            a0 = *reinterpret_cast<const float4*>(&A[(size_t)(rowBase + ar) * K + ac]);
            a1 = *reinterpret_cast<const float4*>(&A[(size_t)(rowBase + ar) * K + ac + 4]);
        }
        for (int k0 = 0; k0 < K; k0 += BK) {
            __syncthreads();
            if constexpr (ASPLIT) {
                *reinterpret_cast<uint4*>(&Alh[ar][ac]) = avh;
                *reinterpret_cast<uint4*>(&All[ar][ac]) = avl;
            } else {
                ushort4 h4, l4;
                h4.x = bf16_rn(a0.x); l4.x = bf16_rn(a0.x - bf16_f32(h4.x));
                h4.y = bf16_rn(a0.y); l4.y = bf16_rn(a0.y - bf16_f32(h4.y));
                h4.z = bf16_rn(a0.z); l4.z = bf16_rn(a0.z - bf16_f32(h4.z));
                h4.w = bf16_rn(a0.w); l4.w = bf16_rn(a0.w - bf16_f32(h4.w));
                *reinterpret_cast<ushort4*>(&Alh[ar][ac]) = h4;
                *reinterpret_cast<ushort4*>(&All[ar][ac]) = l4;
                h4.x = bf16_rn(a1.x); l4.x = bf16_rn(a1.x - bf16_f32(h4.x));
                h4.y = bf16_rn(a1.y); l4.y = bf16_rn(a1.y - bf16_f32(h4.y));
                h4.z = bf16_rn(a1.z); l4.z = bf16_rn(a1.z - bf16_f32(h4.z));
                h4.w = bf16_rn(a1.w); l4.w = bf16_rn(a1.w - bf16_f32(h4.w));
                *reinterpret_cast<ushort4*>(&Alh[ar][ac + 4]) = h4;
                *reinterpret_cast<ushort4*>(&All[ar][ac + 4]) = l4;
            }
            *reinterpret_cast<uint4*>(&Blh[ar][ac]) = bh0;
            *reinterpret_cast<uint4*>(&Bll[ar][ac]) = bl0;
            *reinterpret_cast<uint4*>(&Blh[32 + ar][ac]) = bh1;
            *reinterpret_cast<uint4*>(&Bll[32 + ar][ac]) = bl1;
            __syncthreads();
            int kn = k0 + BK;
            if (kn < K) {
                bh0 = *reinterpret_cast<const uint4*>(&Bh[(size_t)(colBase + ar) * K + kn + ac]);
                bl0 = *reinterpret_cast<const uint4*>(&Bl[(size_t)(colBase + ar) * K + kn + ac]);
                bh1 = *reinterpret_cast<const uint4*>(&Bh[(size_t)(colBase + 32 + ar) * K + kn + ac]);
                bl1 = *reinterpret_cast<const uint4*>(&Bl[(size_t)(colBase + 32 + ar) * K + kn + ac]);
                if constexpr (ASPLIT) {
                    avh = *reinterpret_cast<const uint4*>(&Ah[(size_t)(rowBase + ar) * K + kn + ac]);
                    avl = *reinterpret_cast<const uint4*>(&Al[(size_t)(rowBase + ar) * K + kn + ac]);
                } else {
                    a0 = *reinterpret_cast<const float4*>(&A[(size_t)(rowBase + ar) * K + kn + ac]);
                    a1 = *reinterpret_cast<const float4*>(&A[(size_t)(rowBase + ar) * K + kn + ac + 4]);
                }
            }
            #pragma unroll
            for (int ks = 0; ks < 2; ++ks) {
                int kb = ks * 32 + lk * 8;
                bf16x8v ah = *reinterpret_cast<const bf16x8v*>(&Alh[wr * 16 + lr][kb]);
                bf16x8v al = *reinterpret_cast<const bf16x8v*>(&All[wr * 16 + lr][kb]);
                bf16x8v b0h = *reinterpret_cast<const bf16x8v*>(&Blh[wc * 32 + lr][kb]);
                bf16x8v b0l = *reinterpret_cast<const bf16x8v*>(&Bll[wc * 32 + lr][kb]);
                bf16x8v b1h = *reinterpret_cast<const bf16x8v*>(&Blh[wc * 32 + 16 + lr][kb]);
                bf16x8v b1l = *reinterpret_cast<const bf16x8v*>(&Bll[wc * 32 + 16 + lr][kb]);
                acc0 = __builtin_amdgcn_mfma_f32_16x16x32_bf16(ah, b0h, acc0, 0, 0, 0);
                acc0 = __builtin_amdgcn_mfma_f32_16x16x32_bf16(ah, b0l, acc0, 0, 0, 0);
                acc0 = __builtin_amdgcn_mfma_f32_16x16x32_bf16(al, b0h, acc0, 0, 0, 0);
                acc1 = __builtin_amdgcn_mfma_f32_16x16x32_bf16(ah, b1h, acc1, 0, 0, 0);
                acc1 = __builtin_amdgcn_mfma_f32_16x16x32_bf16(ah, b1l, acc1, 0, 0, 0);
                acc1 = __builtin_amdgcn_mfma_f32_16x16x32_bf16(al, b1h, acc1, 0, 0, 0);
            }
        }
    }
    // ---- write C ----
    int crow = rowBase + wr * 16 + lk * 4;
    int ccol = colBase + wc * 32 + lr;
    #pragma unroll
    for (int r = 0; r < 4; ++r) {
        C[(size_t)(crow + r) * N + ccol]      = acc0[r];
        C[(size_t)(crow + r) * N + ccol + 16] = acc1[r];
    }
    // ---- fused adot epilogue (node-major [n][h] outputs) ----
    int n0 = colBase + wc * 32 + lr;
    int hh = n0 / FO;
    int o0 = n0 % FO;
    int o1 = o0 + 16;
    const float* av = a + hh * 2 * FO;
    float aS0 = av[o0], aS1 = av[o1];
    float aD0 = av[FO + o0], aD1 = av[FO + o1];
    float sv[4], dv[4];
    #pragma unroll
    for (int r = 0; r < 4; ++r) {
        sv[r] = acc0[r] * aS0 + acc1[r] * aS1;
        dv[r] = acc0[r] * aD0 + acc1[r] * aD1;
        #pragma unroll
        for (int msk = 1; msk < 16; msk <<= 1) {
            sv[r] += __shfl_xor(sv[r], msk);
            dv[r] += __shfl_xor(dv[r], msk);
        }
    }
    if constexpr (FO == 64) {
        if (lr == 0) {
            #pragma unroll
            for (int r = 0; r < 4; ++r) {
                reds[wc * 32 + wr * 16 + lk * 4 + r] = sv[r];
                redd[wc * 32 + wr * 16 + lk * 4 + r] = dv[r];
            }
        }
        __syncthreads();
        if (tid < BM) {
            int row = tid;
            asrc[(size_t)(rowBase + row) * NHEADS + by] = reds[row] + reds[32 + row];
            adst[(size_t)(rowBase + row) * NHEADS + by] = redd[row] + redd[32 + row];
        }
        __syncthreads();
    } else {
        if (lr == 0) {
            #pragma unroll
            for (int r = 0; r < 4; ++r) {
                int row = rowBase + wr * 16 + lk * 4 + r;
                asrc[(size_t)row * NHEADS + hh] = sv[r];
                adst[(size_t)row * NHEADS + hh] = dv[r];
            }
        }
    }
}

// ---------------------------------------------------------------------------
// agg body (flash, verbatim): one-pass online softmax + aggregate + ELU.
// ---------------------------------------------------------------------------
template <int FO, bool SPLITOUT>
__device__ inline void agg_body(
    const float* __restrict__ Wh,
    const float* __restrict__ asrc, const float* __restrict__ adst,
    const int* __restrict__ nbr, const int* __restrict__ deg,
    float* __restrict__ out,
    unsigned short* __restrict__ outh, unsigned short* __restrict__ outl,
    int n) {
    int wslot = threadIdx.x >> 6;
    int lane = threadIdx.x & 63;
    int h = wslot;
    int dg = deg[n];
    const int* lst = nbr + n * NBR_STRIDE;
    float my_as = asrc[(size_t)n * NHEADS + h];

    constexpr int STRIDE = NHEADS * FO;
    constexpr int LPR = FO / 4;
    constexpr int NPS = 64 / LPR;
    int sub = lane / LPR;
    int dim4 = (lane % LPR) * 4;
    const float* whp = Wh + h * FO + dim4;

    float m = -1e30f, s = 0.f;
    f32x4 acc = {0.f, 0.f, 0.f, 0.f};

    int k = sub;
    for (; k + NPS < dg; k += 2 * NPS) {
        int cA = lst[k];
        int cB = lst[k + NPS];
        float eA = my_as + adst[(size_t)cA * NHEADS + h];
        float eB = my_as + adst[(size_t)cB * NHEADS + h];
        eA = eA >= 0.f ? eA : 0.2f * eA;
        eB = eB >= 0.f ? eB : 0.2f * eB;
        float4 vA = *reinterpret_cast<const float4*>(&whp[(size_t)cA * STRIDE]);
        float4 vB = *reinterpret_cast<const float4*>(&whp[(size_t)cB * STRIDE]);
        float mn = fmaxf(m, fmaxf(eA, eB));
        float sc = __expf(m - mn);
        float pA = __expf(eA - mn);
        float pB = __expf(eB - mn);
        s = s * sc + pA + pB;
        acc[0] = acc[0] * sc + pA * vA.x + pB * vB.x;
        acc[1] = acc[1] * sc + pA * vA.y + pB * vB.y;
        acc[2] = acc[2] * sc + pA * vA.z + pB * vB.z;
        acc[3] = acc[3] * sc + pA * vA.w + pB * vB.w;
        m = mn;
    }
    if (k < dg) {
        int c = lst[k];
        float e = my_as + adst[(size_t)c * NHEADS + h];
        e = e >= 0.f ? e : 0.2f * e;
        float4 v = *reinterpret_cast<const float4*>(&whp[(size_t)c * STRIDE]);
        float mn = fmaxf(m, e);
        float sc = __expf(m - mn);
        float p = __expf(e - mn);
        s = s * sc + p;
        acc[0] = acc[0] * sc + p * v.x;
        acc[1] = acc[1] * sc + p * v.y;
        acc[2] = acc[2] * sc + p * v.z;
        acc[3] = acc[3] * sc + p * v.w;
        m = mn;
    }
    #pragma unroll
    for (int off = LPR; off < 64; off <<= 1) {
        float m2 = __shfl_xor(m, off);
        float s2 = __shfl_xor(s, off);
        float a0 = __shfl_xor(acc[0], off);
        float a1 = __shfl_xor(acc[1], off);
        float a2 = __shfl_xor(acc[2], off);
        float a3 = __shfl_xor(acc[3], off);
        float mn = fmaxf(m, m2);
        float sa = __expf(m - mn);
        float sb = __expf(m2 - mn);
        s = s * sa + s2 * sb;
        acc[0] = acc[0] * sa + a0 * sb;
        acc[1] = acc[1] * sa + a1 * sb;
        acc[2] = acc[2] * sa + a2 * sb;
        acc[3] = acc[3] * sa + a3 * sb;
        m = mn;
    }
    if (lane < LPR) {
        float inv = 1.0f / s;
        float r0 = acc[0] * inv;
        float r1 = acc[1] * inv;
        float r2 = acc[2] * inv;
        float r3 = acc[3] * inv;
        r0 = r0 > 0.f ? r0 : expm1f(r0);
        r1 = r1 > 0.f ? r1 : expm1f(r1);
        r2 = r2 > 0.f ? r2 : expm1f(r2);
        r3 = r3 > 0.f ? r3 : expm1f(r3);
        size_t idx = (size_t)n * STRIDE + h * FO + dim4;
        if constexpr (SPLITOUT) {
            ushort4 hv, lv;
            hv.x = bf16_rn(r0); lv.x = bf16_rn(r0 - bf16_f32(hv.x));
            hv.y = bf16_rn(r1); lv.y = bf16_rn(r1 - bf16_f32(hv.y));
            hv.z = bf16_rn(r2); lv.z = bf16_rn(r2 - bf16_f32(hv.z));
            hv.w = bf16_rn(r3); lv.w = bf16_rn(r3 - bf16_f32(hv.w));
            *reinterpret_cast<ushort4*>(&outh[idx]) = hv;
            *reinterpret_cast<ushort4*>(&outl[idx]) = lv;
        } else {
            *reinterpret_cast<float4*>(&out[idx]) = make_float4(r0, r1, r2, r3);
        }
    }
}

// ---------------------------------------------------------------------------
// Cooperative mega-kernel v3: 2048 blocks; phase-B roles INTERLEAVED so every
// group of 4 consecutive blocks = 1 gemm + 3 nbr (robust to chunked block->CU
// mapping: MFMA and latency-bound scan co-scheduled on every CU).
// ---------------------------------------------------------------------------
__global__ __launch_bounds__(256, 8) void mega_kernel(
    const float* __restrict__ adj, const float* __restrict__ x,
    const float* __restrict__ W1, const float* __restrict__ a1,
    const float* __restrict__ W2, const float* __restrict__ a2,
    int* __restrict__ nbr, int* __restrict__ deg,
    unsigned short* __restrict__ B1h, unsigned short* __restrict__ B1l,
    unsigned short* __restrict__ B2h, unsigned short* __restrict__ B2l,
    float* __restrict__ Wh1, float* __restrict__ as1, float* __restrict__ ad1,
    unsigned short* __restrict__ h1h, unsigned short* __restrict__ h1l,
    float* __restrict__ Wh2, float* __restrict__ as2, float* __restrict__ ad2,
    float* __restrict__ out) {
    __shared__ __align__(16) char arena[15872];
    cg::grid_group grid = cg::this_grid();
    int b = blockIdx.x;

    // ---- Phase A: pack W hi/lo ----
    {
        int t = b * 256 + (int)threadIdx.x;
        if (t < 256 * 512 + 128 * 256)
            pack_body(W1, W2, B1h, B1l, B2h, B2l, t);
    }
    grid.sync();

    // ---- Phase B (interleaved roles): (b&3)==3 -> gemm1 tile; else nbr ----
    if ((b & 3) == 3) {
        int g = b >> 2;                    // 0..511
        gemm_body<512, 256, 64, 32, false>(arena, x, nullptr, nullptr,
                                           B1h, B1l, a1, Wh1, as1, ad1,
                                           g & 127, g >> 7);
    } else {
        int nb = (b >> 2) * 3 + (b & 3);   // 0..1535
        #pragma unroll
        for (int i = 0; i < 3; ++i) {
            int row = nb + 1536 * i;
            if (row < NNODES) build_nbr_body3(arena, adj, nbr, deg, row);
        }
    }
    grid.sync();

    // ---- Phase C: agg1 (2 nodes/block) ----
    agg_body<64, true>(Wh1, as1, ad1, nbr, deg, nullptr, h1h, h1l, b * 2);
    agg_body<64, true>(Wh1, as1, ad1, nbr, deg, nullptr, h1h, h1l, b * 2 + 1);
    grid.sync();

    // ---- Phase D: gemm2 (every 8th block), BK=32, pre-split A ----
    if ((b & 7) == 7) {
        int g = b >> 3;                    // 0..255
        gemm_body<256, 128, 32, 32, true>(arena, nullptr, h1h, h1l,
                                          B2h, B2l, a2, Wh2, as2, ad2,
                                          g & 127, g >> 7);
    }
    grid.sync();

    // ---- Phase E: agg2 (2 nodes/block) ----
    agg_body<32, false>(Wh2, as2, ad2, nbr, deg, out, nullptr, nullptr, b * 2);
    agg_body<32, false>(Wh2, as2, ad2, nbr, deg, out, nullptr, nullptr, b * 2 + 1);
}

// ---------------------------------------------------------------------------
// Fallback standalone kernels (r19 structure)
// ---------------------------------------------------------------------------
__global__ __launch_bounds__(256) void pack_b_both_kernel(
    const float* __restrict__ W1, const float* __restrict__ W2,
    unsigned short* __restrict__ B1h, unsigned short* __restrict__ B1l,
    unsigned short* __restrict__ B2h, unsigned short* __restrict__ B2l) {
    pack_body(W1, W2, B1h, B1l, B2h, B2l, blockIdx.x * 256 + threadIdx.x);
}

__global__ __launch_bounds__(256) void fused1_kernel(
    const float* __restrict__ adj, int* __restrict__ nbr, int* __restrict__ deg,
    const float* __restrict__ x,
    const unsigned short* __restrict__ B1h, const unsigned short* __restrict__ B1l,
    const float* __restrict__ a1, float* __restrict__ Wh1,
    float* __restrict__ as1, float* __restrict__ ad1) {
    __shared__ __align__(16) char arena[15872];
    int b = blockIdx.x;
    if (b < 512) {
        gemm_body<512, 256, 64, 32, false>(arena, x, nullptr, nullptr,
                                           B1h, B1l, a1, Wh1, as1, ad1,
                                           b & 127, b >> 7);
    } else {
        build_nbr_body3(arena, adj, nbr, deg, b - 512);
    }
}

__global__ __launch_bounds__(256) void gemm2_kernel(
    const unsigned short* __restrict__ Ah, const unsigned short* __restrict__ Al,
    const unsigned short* __restrict__ Bh, const unsigned short* __restrict__ Bl,
    const float* __restrict__ a, float* __restrict__ C,
    float* __restrict__ asrc, float* __restrict__ adst) {
    __shared__ __align__(16) char arena[28160];
    gemm_body<256, 128, 32, 64, true>(arena, nullptr, Ah, Al, Bh, Bl,
                                      a, C, asrc, adst, blockIdx.x, blockIdx.y);
}

template <int FO, bool SPLITOUT>
__global__ __launch_bounds__(256) void agg_kernel(
    const float* __restrict__ Wh,
    const float* __restrict__ asrc, const float* __restrict__ adst,
    const int* __restrict__ nbr, const int* __restrict__ deg,
    float* __restrict__ out,
    unsigned short* __restrict__ outh, unsigned short* __restrict__ outl) {
    agg_body<FO, SPLITOUT>(Wh, asrc, adst, nbr, deg, out, outh, outl, blockIdx.x);
}

// ---------------------------------------------------------------------------
extern "C" void kernel_launch(void* const* d_in, const int* in_sizes, int n_in,
                              void* d_out, int out_size, void* d_ws, size_t ws_size,
                              hipStream_t stream) {
    const float* x   = (const float*)d_in[0];
    const float* adj = (const float*)d_in[1];
    const float* W1  = (const float*)d_in[2];
    const float* a1  = (const float*)d_in[3];
    const float* W2  = (const float*)d_in[4];
    const float* a2  = (const float*)d_in[5];
    float* outp = (float*)d_out;

    char* p = (char*)d_ws;
    auto alloc = [&](size_t bytes) -> void* {
        void* r = (void*)p;
        p += (bytes + 255) & ~(size_t)255;
        return r;
    };
    int*   nbr = (int*)alloc((size_t)NNODES * NBR_STRIDE * 4);
    int*   deg = (int*)alloc((size_t)NNODES * 4);
    unsigned short* B1h = (unsigned short*)alloc((size_t)256 * 512 * 2);
    unsigned short* B1l = (unsigned short*)alloc((size_t)256 * 512 * 2);
    unsigned short* B2h = (unsigned short*)alloc((size_t)128 * 256 * 2);
    unsigned short* B2l = (unsigned short*)alloc((size_t)128 * 256 * 2);
    float* Wh1 = (float*)alloc((size_t)NNODES * 256 * 4);
    float* as1 = (float*)alloc((size_t)NHEADS * NNODES * 4);
    float* ad1 = (float*)alloc((size_t)NHEADS * NNODES * 4);
    unsigned short* h1h = (unsigned short*)alloc((size_t)NNODES * 256 * 2);
    unsigned short* h1l = (unsigned short*)alloc((size_t)NNODES * 256 * 2);
    float* Wh2 = (float*)alloc((size_t)NNODES * 128 * 4);
    float* as2 = (float*)alloc((size_t)NHEADS * NNODES * 4);
    float* ad2 = (float*)alloc((size_t)NHEADS * NNODES * 4);

    int blocksPerCU = 0;
    hipError_t qe = hipOccupancyMaxActiveBlocksPerMultiprocessor(
        &blocksPerCU, (const void*)mega_kernel, 256, 0);
    bool coop = (qe == hipSuccess) && (blocksPerCU * 256 >= NBLK);

    if (coop) {
        void* args[] = {
            (void*)&adj, (void*)&x, (void*)&W1, (void*)&a1, (void*)&W2, (void*)&a2,
            (void*)&nbr, (void*)&deg, (void*)&B1h, (void*)&B1l, (void*)&B2h, (void*)&B2l,
            (void*)&Wh1, (void*)&as1, (void*)&ad1, (void*)&h1h, (void*)&h1l,
            (void*)&Wh2, (void*)&as2, (void*)&ad2, (void*)&outp
        };
        hipError_t le = hipLaunchCooperativeKernel((const void*)mega_kernel,
                                                   dim3(NBLK), dim3(256),
                                                   args, 0, stream);
        if (le == hipSuccess) return;
        (void)hipGetLastError();
    }

    // ---- fallback: 5-kernel path ----
    pack_b_both_kernel<<<dim3((256 * 512 + 128 * 256) / 256), dim3(256), 0, stream>>>(
        W1, W2, B1h, B1l, B2h, B2l);
    fused1_kernel<<<dim3(512 + NNODES), dim3(256), 0, stream>>>(
        adj, nbr, deg, x, B1h, B1l, a1, Wh1, as1, ad1);
    agg_kernel<64, true><<<dim3(NNODES), dim3(256), 0, stream>>>(
        Wh1, as1, ad1, nbr, deg, nullptr, h1h, h1l);
    gemm2_kernel<<<dim3(NNODES / 32, 2), dim3(256), 0, stream>>>(
        h1h, h1l, B2h, B2l, a2, Wh2, as2, ad2);
    agg_kernel<32, false><<<dim3(NNODES), dim3(256), 0, stream>>>(
        Wh2, as2, ad2, nbr, deg, outp, nullptr, nullptr);
}

// Round 21
// 63.324 us; speedup vs baseline: 1.0158x; 1.0158x over previous
//
#include <hip/hip_runtime.h>
#include <hip/hip_bf16.h>
#include <hip/hip_cooperative_groups.h>
#include <cstdint>
#include <cstddef>

namespace cg = cooperative_groups;

#define NNODES 4096
#define NHEADS 4
#define NBR_STRIDE 128
#define NBLK 2048
#define ARENA_SZ 18560   // 16KB DMA stage + 2KB slots + cnts (nbr); gemm needs 15872

typedef __attribute__((ext_vector_type(8))) short bf16x8v;
typedef __attribute__((ext_vector_type(4))) float f32x4;

__device__ inline unsigned short bf16_rn(float f) {
    unsigned int u = __float_as_uint(f);
    u += 0x7FFFu + ((u >> 16) & 1u);
    return (unsigned short)(u >> 16);
}
__device__ inline float bf16_f32(unsigned short s) {
    return __uint_as_float(((unsigned int)s) << 16);
}

// ---------------------------------------------------------------------------
// nbr v4: DMA-staged scan. Each wave issues 4x global_load_lds (16B/lane,
// linear LDS dest = wave-uniform base + lane*16 -- the required layout),
// waits vmcnt(0), then reads its quarter-row from LDS and runs the identical
// ballot/compaction as v3. No VGPR-load/waitcnt coupling in the load path.
// Arena layout: stage 0..16383, slots 16384..18431, cnts 18432..18447.
// ---------------------------------------------------------------------------
__device__ inline void build_nbr_body4(
    char* arena,
    const float* __restrict__ adj, int* __restrict__ nbr, int* __restrict__ deg,
    int row) {
    float* stage = (float*)arena;                   // [4096] floats
    int* slots = (int*)(arena + 16384);             // [4][128]
    int* cnts  = (int*)(arena + 16384 + 2048);      // [4]
    int wave = threadIdx.x >> 6;
    int lane = threadIdx.x & 63;
    const char* src = (const char*)(adj + (size_t)row * NNODES) + wave * 4096 + lane * 16;
    char* dst = (char*)stage + wave * 4096;
    #pragma unroll
    for (int it = 0; it < 4; ++it) {
        __builtin_amdgcn_global_load_lds(
            (const __attribute__((address_space(1))) unsigned int*)(src + it * 1024),
            (__attribute__((address_space(3))) unsigned int*)(dst + it * 1024),
            16, 0, 0);
    }
    asm volatile("s_waitcnt vmcnt(0)" ::: "memory");
    __builtin_amdgcn_sched_barrier(0);
    const float4* quarter = reinterpret_cast<const float4*>(stage + wave * 1024);
    float4 v[4];
    #pragma unroll
    for (int it = 0; it < 4; ++it) v[it] = quarter[it * 64 + lane];
    unsigned long long lt = (1ull << lane) - 1ull;
    int* slot = slots + wave * 128;
    int base = 0;
    #pragma unroll
    for (int it = 0; it < 4; ++it) {
        bool b0 = v[it].x > 0.f, b1 = v[it].y > 0.f, b2 = v[it].z > 0.f, b3 = v[it].w > 0.f;
        unsigned long long m0 = __ballot(b0);
        unsigned long long m1 = __ballot(b1);
        unsigned long long m2 = __ballot(b2);
        unsigned long long m3 = __ballot(b3);
        int pre = __popcll(m0 & lt) + __popcll(m1 & lt) +
                  __popcll(m2 & lt) + __popcll(m3 & lt);
        int pos = base + pre;
        int colb = wave * 1024 + it * 256 + lane * 4;
        if (b0) { if (pos < NBR_STRIDE) slot[pos] = colb;     pos++; }
        if (b1) { if (pos < NBR_STRIDE) slot[pos] = colb + 1; pos++; }
        if (b2) { if (pos < NBR_STRIDE) slot[pos] = colb + 2; pos++; }
        if (b3) { if (pos < NBR_STRIDE) slot[pos] = colb + 3; pos++; }
        base += __popcll(m0) + __popcll(m1) + __popcll(m2) + __popcll(m3);
    }
    if (lane == 0) cnts[wave] = base < NBR_STRIDE ? base : NBR_STRIDE;
    __syncthreads();
    int c0 = cnts[0], c1 = cnts[1], c2 = cnts[2];
    int tot = c0 + c1 + c2 + cnts[3];
    if (tot > NBR_STRIDE) tot = NBR_STRIDE;
    int t = threadIdx.x;
    if (t < tot) {
        int val;
        if (t < c0)                val = slots[t];
        else if (t < c0 + c1)      val = slots[128 + t - c0];
        else if (t < c0 + c1 + c2) val = slots[256 + t - c0 - c1];
        else                       val = slots[384 + t - c0 - c1 - c2];
        nbr[row * NBR_STRIDE + t] = val;
    }
    if (t == 0) deg[row] = tot;
    __syncthreads();   // arena safe for reuse
}

// ---------------------------------------------------------------------------
// pack body: both layers' W -> transposed hi/lo bf16
// ---------------------------------------------------------------------------
__device__ inline void pack_body(
    const float* __restrict__ W1, const float* __restrict__ W2,
    unsigned short* __restrict__ B1h, unsigned short* __restrict__ B1l,
    unsigned short* __restrict__ B2h, unsigned short* __restrict__ B2l,
    int t) {
    if (t < 256 * 512) {
        int n = t >> 9, k = t & 511;
        int h = n >> 6, o = n & 63;
        float v = W1[((size_t)h * 512 + k) * 64 + o];
        unsigned short hi = bf16_rn(v);
        B1h[t] = hi;
        B1l[t] = bf16_rn(v - bf16_f32(hi));
    } else {
        int u = t - 256 * 512;
        if (u < 128 * 256) {
            int n = u >> 8, k = u & 255;
            int h = n >> 5, o = n & 31;
            float v = W2[((size_t)h * 256 + k) * 32 + o];
            unsigned short hi = bf16_rn(v);
            B2h[u] = hi;
            B2l[u] = bf16_rn(v - bf16_f32(hi));
        }
    }
}

// ---------------------------------------------------------------------------
// gemm body, software-pipelined (r19 verbatim).
// ---------------------------------------------------------------------------
template <int K, int N, int FO, int BK, bool ASPLIT>
__device__ inline void gemm_body(
    char* arena,
    const float* __restrict__ A,
    const unsigned short* __restrict__ Ah, const unsigned short* __restrict__ Al,
    const unsigned short* __restrict__ Bh, const unsigned short* __restrict__ Bl,
    const float* __restrict__ a, float* __restrict__ C,
    float* __restrict__ asrc, float* __restrict__ adst,
    int bx, int by) {
    constexpr int BM = 32, BN = 64, LP = BK + 8;
    constexpr int ALD = BM * LP * 2;
    constexpr int BLD = BN * LP * 2;
    typedef unsigned short (*lds_t)[LP];
    lds_t Alh = (lds_t)(arena);
    lds_t All = (lds_t)(arena + ALD);
    lds_t Blh = (lds_t)(arena + 2 * ALD);
    lds_t Bll = (lds_t)(arena + 2 * ALD + BLD);
    float* reds = (float*)(arena + 2 * ALD + 2 * BLD);          // [2][32]
    float* redd = (float*)(arena + 2 * ALD + 2 * BLD + 256);    // [2][32]
    int tid = threadIdx.x;
    int wave = tid >> 6, lane = tid & 63;
    int rowBase = bx * BM;
    int colBase = by * BN;
    int wr = wave >> 1, wc = wave & 1;
    int lr = lane & 15, lk = lane >> 4;
    f32x4 acc0 = {0.f, 0.f, 0.f, 0.f};
    f32x4 acc1 = {0.f, 0.f, 0.f, 0.f};

    if constexpr (BK == 32) {
        int ar = tid >> 3, acf = (tid & 7) * 4;     // A: 32x32
        int br = tid >> 2, bc = (tid & 3) * 8;      // B: 64x32
        uint4 bh = *reinterpret_cast<const uint4*>(&Bh[(size_t)(colBase + br) * K + bc]);
        uint4 bl = *reinterpret_cast<const uint4*>(&Bl[(size_t)(colBase + br) * K + bc]);
        uint2 avh, avl; float4 a0;
        if constexpr (ASPLIT) {
            avh = *reinterpret_cast<const uint2*>(&Ah[(size_t)(rowBase + ar) * K + acf]);
            avl = *reinterpret_cast<const uint2*>(&Al[(size_t)(rowBase + ar) * K + acf]);
        } else {
            a0 = *reinterpret_cast<const float4*>(&A[(size_t)(rowBase + ar) * K + acf]);
        }
        for (int k0 = 0; k0 < K; k0 += BK) {
            __syncthreads();
            if constexpr (ASPLIT) {
                *reinterpret_cast<uint2*>(&Alh[ar][acf]) = avh;
                *reinterpret_cast<uint2*>(&All[ar][acf]) = avl;
            } else {
                ushort4 h4, l4;
                h4.x = bf16_rn(a0.x); l4.x = bf16_rn(a0.x - bf16_f32(h4.x));
                h4.y = bf16_rn(a0.y); l4.y = bf16_rn(a0.y - bf16_f32(h4.y));
                h4.z = bf16_rn(a0.z); l4.z = bf16_rn(a0.z - bf16_f32(h4.z));
                h4.w = bf16_rn(a0.w); l4.w = bf16_rn(a0.w - bf16_f32(h4.w));
                *reinterpret_cast<ushort4*>(&Alh[ar][acf]) = h4;
                *reinterpret_cast<ushort4*>(&All[ar][acf]) = l4;
            }
            *reinterpret_cast<uint4*>(&Blh[br][bc]) = bh;
            *reinterpret_cast<uint4*>(&Bll[br][bc]) = bl;
            __syncthreads();
            int kn = k0 + BK;
            if (kn < K) {
                bh = *reinterpret_cast<const uint4*>(&Bh[(size_t)(colBase + br) * K + kn + bc]);
                bl = *reinterpret_cast<const uint4*>(&Bl[(size_t)(colBase + br) * K + kn + bc]);
                if constexpr (ASPLIT) {
                    avh = *reinterpret_cast<const uint2*>(&Ah[(size_t)(rowBase + ar) * K + kn + acf]);
                    avl = *reinterpret_cast<const uint2*>(&Al[(size_t)(rowBase + ar) * K + kn + acf]);
                } else {
                    a0 = *reinterpret_cast<const float4*>(&A[(size_t)(rowBase + ar) * K + kn + acf]);
                }
            }
            int kb = lk * 8;
            bf16x8v ah = *reinterpret_cast<const bf16x8v*>(&Alh[wr * 16 + lr][kb]);
            bf16x8v al = *reinterpret_cast<const bf16x8v*>(&All[wr * 16 + lr][kb]);
            bf16x8v b0h = *reinterpret_cast<const bf16x8v*>(&Blh[wc * 32 + lr][kb]);
            bf16x8v b0l = *reinterpret_cast<const bf16x8v*>(&Bll[wc * 32 + lr][kb]);
            bf16x8v b1h = *reinterpret_cast<const bf16x8v*>(&Blh[wc * 32 + 16 + lr][kb]);
            bf16x8v b1l = *reinterpret_cast<const bf16x8v*>(&Bll[wc * 32 + 16 + lr][kb]);
            acc0 = __builtin_amdgcn_mfma_f32_16x16x32_bf16(ah, b0h, acc0, 0, 0, 0);
            acc0 = __builtin_amdgcn_mfma_f32_16x16x32_bf16(ah, b0l, acc0, 0, 0, 0);
            acc0 = __builtin_amdgcn_mfma_f32_16x16x32_bf16(al, b0h, acc0, 0, 0, 0);
            acc1 = __builtin_amdgcn_mfma_f32_16x16x32_bf16(ah, b1h, acc1, 0, 0, 0);
            acc1 = __builtin_amdgcn_mfma_f32_16x16x32_bf16(ah, b1l, acc1, 0, 0, 0);
            acc1 = __builtin_amdgcn_mfma_f32_16x16x32_bf16(al, b1h, acc1, 0, 0, 0);
        }
    } else {   // BK == 64
        int ar = tid >> 3, ac = (tid & 7) * 8;
        uint4 bh0 = *reinterpret_cast<const uint4*>(&Bh[(size_t)(colBase + ar) * K + ac]);
        uint4 bl0 = *reinterpret_cast<const uint4*>(&Bl[(size_t)(colBase + ar) * K + ac]);
        uint4 bh1 = *reinterpret_cast<const uint4*>(&Bh[(size_t)(colBase + 32 + ar) * K + ac]);
        uint4 bl1 = *reinterpret_cast<const uint4*>(&Bl[(size_t)(colBase + 32 + ar) * K + ac]);
        uint4 avh, avl; float4 a0, a1;
        if constexpr (ASPLIT) {
            avh = *reinterpret_cast<const uint4*>(&Ah[(size_t)(rowBase + ar) * K + ac]);
            avl = *reinterpret_cast<const uint4*>(&Al[(size_t)(rowBase + ar) * K + ac]);
        } else {
            a0 = *reinterpret_cast<const float4*>(&A[(size_t)(rowBase + ar) * K + ac]);
            a1 = *reinterpret_cast<const float4*>(&A[(size_t)(rowBase + ar) * K + ac + 4]);
        }
        for (int k0 = 0; k0 < K; k0 += BK) {
            __syncthreads();
            if constexpr (ASPLIT) {
                *reinterpret_cast<uint4*>(&Alh[ar][ac]) = avh;
                *reinterpret_cast<uint4*>(&All[ar][ac]) = avl;
            } else {
                ushort4 h4, l4;
                h4.x = bf16_rn(a0.x); l4.x = bf16_rn(a0.x - bf16_f32(h4.x));
                h4.y = bf16_rn(a0.y); l4.y = bf16_rn(a0.y - bf16_f32(h4.y));
                h4.z = bf16_rn(a0.z); l4.z = bf16_rn(a0.z - bf16_f32(h4.z));
                h4.w = bf16_rn(a0.w); l4.w = bf16_rn(a0.w - bf16_f32(h4.w));
                *reinterpret_cast<ushort4*>(&Alh[ar][ac]) = h4;
                *reinterpret_cast<ushort4*>(&All[ar][ac]) = l4;
                h4.x = bf16_rn(a1.x); l4.x = bf16_rn(a1.x - bf16_f32(h4.x));
                h4.y = bf16_rn(a1.y); l4.y = bf16_rn(a1.y - bf16_f32(h4.y));
                h4.z = bf16_rn(a1.z); l4.z = bf16_rn(a1.z - bf16_f32(h4.z));
                h4.w = bf16_rn(a1.w); l4.w = bf16_rn(a1.w - bf16_f32(h4.w));
                *reinterpret_cast<ushort4*>(&Alh[ar][ac + 4]) = h4;
                *reinterpret_cast<ushort4*>(&All[ar][ac + 4]) = l4;
            }
            *reinterpret_cast<uint4*>(&Blh[ar][ac]) = bh0;
            *reinterpret_cast<uint4*>(&Bll[ar][ac]) = bl0;
            *reinterpret_cast<uint4*>(&Blh[32 + ar][ac]) = bh1;
            *reinterpret_cast<uint4*>(&Bll[32 + ar][ac]) = bl1;
            __syncthreads();
            int kn = k0 + BK;
            if (kn < K) {
                bh0 = *reinterpret_cast<const uint4*>(&Bh[(size_t)(colBase + ar) * K + kn + ac]);
                bl0 = *reinterpret_cast<const uint4*>(&Bl[(size_t)(colBase + ar) * K + kn + ac]);
                bh1 = *reinterpret_cast<const uint4*>(&Bh[(size_t)(colBase + 32 + ar) * K + kn + ac]);
                bl1 = *reinterpret_cast<const uint4*>(&Bl[(size_t)(colBase + 32 + ar) * K + kn + ac]);
                if constexpr (ASPLIT) {
                    avh = *reinterpret_cast<const uint4*>(&Ah[(size_t)(rowBase + ar) * K + kn + ac]);
                    avl = *reinterpret_cast<const uint4*>(&Al[(size_t)(rowBase + ar) * K + kn + ac]);
                } else {
                    a0 = *reinterpret_cast<const float4*>(&A[(size_t)(rowBase + ar) * K + kn + ac]);
                    a1 = *reinterpret_cast<const float4*>(&A[(size_t)(rowBase + ar) * K + kn + ac + 4]);
                }
            }
            #pragma unroll
            for (int ks = 0; ks < 2; ++ks) {
                int kb = ks * 32 + lk * 8;
                bf16x8v ah = *reinterpret_cast<const bf16x8v*>(&Alh[wr * 16 + lr][kb]);
                bf16x8v al = *reinterpret_cast<const bf16x8v*>(&All[wr * 16 + lr][kb]);
                bf16x8v b0h = *reinterpret_cast<const bf16x8v*>(&Blh[wc * 32 + lr][kb]);
                bf16x8v b0l = *reinterpret_cast<const bf16x8v*>(&Bll[wc * 32 + lr][kb]);
                bf16x8v b1h = *reinterpret_cast<const bf16x8v*>(&Blh[wc * 32 + 16 + lr][kb]);
                bf16x8v b1l = *reinterpret_cast<const bf16x8v*>(&Bll[wc * 32 + 16 + lr][kb]);
                acc0 = __builtin_amdgcn_mfma_f32_16x16x32_bf16(ah, b0h, acc0, 0, 0, 0);
                acc0 = __builtin_amdgcn_mfma_f32_16x16x32_bf16(ah, b0l, acc0, 0, 0, 0);
                acc0 = __builtin_amdgcn_mfma_f32_16x16x32_bf16(al, b0h, acc0, 0, 0, 0);
                acc1 = __builtin_amdgcn_mfma_f32_16x16x32_bf16(ah, b1h, acc1, 0, 0, 0);
                acc1 = __builtin_amdgcn_mfma_f32_16x16x32_bf16(ah, b1l, acc1, 0, 0, 0);
                acc1 = __builtin_amdgcn_mfma_f32_16x16x32_bf16(al, b1h, acc1, 0, 0, 0);
            }
        }
    }
    // ---- write C ----
    int crow = rowBase + wr * 16 + lk * 4;
    int ccol = colBase + wc * 32 + lr;
    #pragma unroll
    for (int r = 0; r < 4; ++r) {
        C[(size_t)(crow + r) * N + ccol]      = acc0[r];
        C[(size_t)(crow + r) * N + ccol + 16] = acc1[r];
    }
    // ---- fused adot epilogue (node-major [n][h] outputs) ----
    int n0 = colBase + wc * 32 + lr;
    int hh = n0 / FO;
    int o0 = n0 % FO;
    int o1 = o0 + 16;
    const float* av = a + hh * 2 * FO;
    float aS0 = av[o0], aS1 = av[o1];
    float aD0 = av[FO + o0], aD1 = av[FO + o1];
    float sv[4], dv[4];
    #pragma unroll
    for (int r = 0; r < 4; ++r) {
        sv[r] = acc0[r] * aS0 + acc1[r] * aS1;
        dv[r] = acc0[r] * aD0 + acc1[r] * aD1;
        #pragma unroll
        for (int msk = 1; msk < 16; msk <<= 1) {
            sv[r] += __shfl_xor(sv[r], msk);
            dv[r] += __shfl_xor(dv[r], msk);
        }
    }
    if constexpr (FO == 64) {
        if (lr == 0) {
            #pragma unroll
            for (int r = 0; r < 4; ++r) {
                reds[wc * 32 + wr * 16 + lk * 4 + r] = sv[r];
                redd[wc * 32 + wr * 16 + lk * 4 + r] = dv[r];
            }
        }
        __syncthreads();
        if (tid < BM) {
            int row = tid;
            asrc[(size_t)(rowBase + row) * NHEADS + by] = reds[row] + reds[32 + row];
            adst[(size_t)(rowBase + row) * NHEADS + by] = redd[row] + redd[32 + row];
        }
        __syncthreads();
    } else {
        if (lr == 0) {
            #pragma unroll
            for (int r = 0; r < 4; ++r) {
                int row = rowBase + wr * 16 + lk * 4 + r;
                asrc[(size_t)row * NHEADS + hh] = sv[r];
                adst[(size_t)row * NHEADS + hh] = dv[r];
            }
        }
    }
}

// ---------------------------------------------------------------------------
// agg body (flash, verbatim): one-pass online softmax + aggregate + ELU.
// ---------------------------------------------------------------------------
template <int FO, bool SPLITOUT>
__device__ inline void agg_body(
    const float* __restrict__ Wh,
    const float* __restrict__ asrc, const float* __restrict__ adst,
    const int* __restrict__ nbr, const int* __restrict__ deg,
    float* __restrict__ out,
    unsigned short* __restrict__ outh, unsigned short* __restrict__ outl,
    int n) {
    int wslot = threadIdx.x >> 6;
    int lane = threadIdx.x & 63;
    int h = wslot;
    int dg = deg[n];
    const int* lst = nbr + n * NBR_STRIDE;
    float my_as = asrc[(size_t)n * NHEADS + h];

    constexpr int STRIDE = NHEADS * FO;
    constexpr int LPR = FO / 4;
    constexpr int NPS = 64 / LPR;
    int sub = lane / LPR;
    int dim4 = (lane % LPR) * 4;
    const float* whp = Wh + h * FO + dim4;

    float m = -1e30f, s = 0.f;
    f32x4 acc = {0.f, 0.f, 0.f, 0.f};

    int k = sub;
    for (; k + NPS < dg; k += 2 * NPS) {
        int cA = lst[k];
        int cB = lst[k + NPS];
        float eA = my_as + adst[(size_t)cA * NHEADS + h];
        float eB = my_as + adst[(size_t)cB * NHEADS + h];
        eA = eA >= 0.f ? eA : 0.2f * eA;
        eB = eB >= 0.f ? eB : 0.2f * eB;
        float4 vA = *reinterpret_cast<const float4*>(&whp[(size_t)cA * STRIDE]);
        float4 vB = *reinterpret_cast<const float4*>(&whp[(size_t)cB * STRIDE]);
        float mn = fmaxf(m, fmaxf(eA, eB));
        float sc = __expf(m - mn);
        float pA = __expf(eA - mn);
        float pB = __expf(eB - mn);
        s = s * sc + pA + pB;
        acc[0] = acc[0] * sc + pA * vA.x + pB * vB.x;
        acc[1] = acc[1] * sc + pA * vA.y + pB * vB.y;
        acc[2] = acc[2] * sc + pA * vA.z + pB * vB.z;
        acc[3] = acc[3] * sc + pA * vA.w + pB * vB.w;
        m = mn;
    }
    if (k < dg) {
        int c = lst[k];
        float e = my_as + adst[(size_t)c * NHEADS + h];
        e = e >= 0.f ? e : 0.2f * e;
        float4 v = *reinterpret_cast<const float4*>(&whp[(size_t)c * STRIDE]);
        float mn = fmaxf(m, e);
        float sc = __expf(m - mn);
        float p = __expf(e - mn);
        s = s * sc + p;
        acc[0] = acc[0] * sc + p * v.x;
        acc[1] = acc[1] * sc + p * v.y;
        acc[2] = acc[2] * sc + p * v.z;
        acc[3] = acc[3] * sc + p * v.w;
        m = mn;
    }
    #pragma unroll
    for (int off = LPR; off < 64; off <<= 1) {
        float m2 = __shfl_xor(m, off);
        float s2 = __shfl_xor(s, off);
        float a0 = __shfl_xor(acc[0], off);
        float a1 = __shfl_xor(acc[1], off);
        float a2 = __shfl_xor(acc[2], off);
        float a3 = __shfl_xor(acc[3], off);
        float mn = fmaxf(m, m2);
        float sa = __expf(m - mn);
        float sb = __expf(m2 - mn);
        s = s * sa + s2 * sb;
        acc[0] = acc[0] * sa + a0 * sb;
        acc[1] = acc[1] * sa + a1 * sb;
        acc[2] = acc[2] * sa + a2 * sb;
        acc[3] = acc[3] * sa + a3 * sb;
        m = mn;
    }
    if (lane < LPR) {
        float inv = 1.0f / s;
        float r0 = acc[0] * inv;
        float r1 = acc[1] * inv;
        float r2 = acc[2] * inv;
        float r3 = acc[3] * inv;
        r0 = r0 > 0.f ? r0 : expm1f(r0);
        r1 = r1 > 0.f ? r1 : expm1f(r1);
        r2 = r2 > 0.f ? r2 : expm1f(r2);
        r3 = r3 > 0.f ? r3 : expm1f(r3);
        size_t idx = (size_t)n * STRIDE + h * FO + dim4;
        if constexpr (SPLITOUT) {
            ushort4 hv, lv;
            hv.x = bf16_rn(r0); lv.x = bf16_rn(r0 - bf16_f32(hv.x));
            hv.y = bf16_rn(r1); lv.y = bf16_rn(r1 - bf16_f32(hv.y));
            hv.z = bf16_rn(r2); lv.z = bf16_rn(r2 - bf16_f32(hv.z));
            hv.w = bf16_rn(r3); lv.w = bf16_rn(r3 - bf16_f32(hv.w));
            *reinterpret_cast<ushort4*>(&outh[idx]) = hv;
            *reinterpret_cast<ushort4*>(&outl[idx]) = lv;
        } else {
            *reinterpret_cast<float4*>(&out[idx]) = make_float4(r0, r1, r2, r3);
        }
    }
}

// ---------------------------------------------------------------------------
// Cooperative mega-kernel v4: 2048 blocks; phase-B roles interleaved; nbr
// staged via global_load_lds DMA (v4 body).
// ---------------------------------------------------------------------------
__global__ __launch_bounds__(256, 8) void mega_kernel(
    const float* __restrict__ adj, const float* __restrict__ x,
    const float* __restrict__ W1, const float* __restrict__ a1,
    const float* __restrict__ W2, const float* __restrict__ a2,
    int* __restrict__ nbr, int* __restrict__ deg,
    unsigned short* __restrict__ B1h, unsigned short* __restrict__ B1l,
    unsigned short* __restrict__ B2h, unsigned short* __restrict__ B2l,
    float* __restrict__ Wh1, float* __restrict__ as1, float* __restrict__ ad1,
    unsigned short* __restrict__ h1h, unsigned short* __restrict__ h1l,
    float* __restrict__ Wh2, float* __restrict__ as2, float* __restrict__ ad2,
    float* __restrict__ out) {
    __shared__ __align__(16) char arena[ARENA_SZ];
    cg::grid_group grid = cg::this_grid();
    int b = blockIdx.x;

    // ---- Phase A: pack W hi/lo ----
    {
        int t = b * 256 + (int)threadIdx.x;
        if (t < 256 * 512 + 128 * 256)
            pack_body(W1, W2, B1h, B1l, B2h, B2l, t);
    }
    grid.sync();

    // ---- Phase B (interleaved roles): (b&3)==3 -> gemm1 tile; else nbr ----
    if ((b & 3) == 3) {
        int g = b >> 2;                    // 0..511
        gemm_body<512, 256, 64, 32, false>(arena, x, nullptr, nullptr,
                                           B1h, B1l, a1, Wh1, as1, ad1,
                                           g & 127, g >> 7);
    } else {
        int nb = (b >> 2) * 3 + (b & 3);   // 0..1535
        #pragma unroll
        for (int i = 0; i < 3; ++i) {
            int row = nb + 1536 * i;
            if (row < NNODES) build_nbr_body4(arena, adj, nbr, deg, row);
        }
    }
    grid.sync();

    // ---- Phase C: agg1 (2 nodes/block) ----
    agg_body<64, true>(Wh1, as1, ad1, nbr, deg, nullptr, h1h, h1l, b * 2);
    agg_body<64, true>(Wh1, as1, ad1, nbr, deg, nullptr, h1h, h1l, b * 2 + 1);
    grid.sync();

    // ---- Phase D: gemm2 (every 8th block), BK=32, pre-split A ----
    if ((b & 7) == 7) {
        int g = b >> 3;                    // 0..255
        gemm_body<256, 128, 32, 32, true>(arena, nullptr, h1h, h1l,
                                          B2h, B2l, a2, Wh2, as2, ad2,
                                          g & 127, g >> 7);
    }
    grid.sync();

    // ---- Phase E: agg2 (2 nodes/block) ----
    agg_body<32, false>(Wh2, as2, ad2, nbr, deg, out, nullptr, nullptr, b * 2);
    agg_body<32, false>(Wh2, as2, ad2, nbr, deg, out, nullptr, nullptr, b * 2 + 1);
}

// ---------------------------------------------------------------------------
// Fallback standalone kernels (v4 nbr)
// ---------------------------------------------------------------------------
__global__ __launch_bounds__(256) void pack_b_both_kernel(
    const float* __restrict__ W1, const float* __restrict__ W2,
    unsigned short* __restrict__ B1h, unsigned short* __restrict__ B1l,
    unsigned short* __restrict__ B2h, unsigned short* __restrict__ B2l) {
    pack_body(W1, W2, B1h, B1l, B2h, B2l, blockIdx.x * 256 + threadIdx.x);
}

__global__ __launch_bounds__(256) void fused1_kernel(
    const float* __restrict__ adj, int* __restrict__ nbr, int* __restrict__ deg,
    const float* __restrict__ x,
    const unsigned short* __restrict__ B1h, const unsigned short* __restrict__ B1l,
    const float* __restrict__ a1, float* __restrict__ Wh1,
    float* __restrict__ as1, float* __restrict__ ad1) {
    __shared__ __align__(16) char arena[ARENA_SZ];
    int b = blockIdx.x;
    if (b < 512) {
        gemm_body<512, 256, 64, 32, false>(arena, x, nullptr, nullptr,
                                           B1h, B1l, a1, Wh1, as1, ad1,
                                           b & 127, b >> 7);
    } else {
        build_nbr_body4(arena, adj, nbr, deg, b - 512);
    }
}

__global__ __launch_bounds__(256) void gemm2_kernel(
    const unsigned short* __restrict__ Ah, const unsigned short* __restrict__ Al,
    const unsigned short* __restrict__ Bh, const unsigned short* __restrict__ Bl,
    const float* __restrict__ a, float* __restrict__ C,
    float* __restrict__ asrc, float* __restrict__ adst) {
    __shared__ __align__(16) char arena[28160];
    gemm_body<256, 128, 32, 64, true>(arena, nullptr, Ah, Al, Bh, Bl,
                                      a, C, asrc, adst, blockIdx.x, blockIdx.y);
}

template <int FO, bool SPLITOUT>
__global__ __launch_bounds__(256) void agg_kernel(
    const float* __restrict__ Wh,
    const float* __restrict__ asrc, const float* __restrict__ adst,
    const int* __restrict__ nbr, const int* __restrict__ deg,
    float* __restrict__ out,
    unsigned short* __restrict__ outh, unsigned short* __restrict__ outl) {
    agg_body<FO, SPLITOUT>(Wh, asrc, adst, nbr, deg, out, outh, outl, blockIdx.x);
}

// ---------------------------------------------------------------------------
extern "C" void kernel_launch(void* const* d_in, const int* in_sizes, int n_in,
                              void* d_out, int out_size, void* d_ws, size_t ws_size,
                              hipStream_t stream) {
    const float* x   = (const float*)d_in[0];
    const float* adj = (const float*)d_in[1];
    const float* W1  = (const float*)d_in[2];
    const float* a1  = (const float*)d_in[3];
    const float* W2  = (const float*)d_in[4];
    const float* a2  = (const float*)d_in[5];
    float* outp = (float*)d_out;

    char* p = (char*)d_ws;
    auto alloc = [&](size_t bytes) -> void* {
        void* r = (void*)p;
        p += (bytes + 255) & ~(size_t)255;
        return r;
    };
    int*   nbr = (int*)alloc((size_t)NNODES * NBR_STRIDE * 4);
    int*   deg = (int*)alloc((size_t)NNODES * 4);
    unsigned short* B1h = (unsigned short*)alloc((size_t)256 * 512 * 2);
    unsigned short* B1l = (unsigned short*)alloc((size_t)256 * 512 * 2);
    unsigned short* B2h = (unsigned short*)alloc((size_t)128 * 256 * 2);
    unsigned short* B2l = (unsigned short*)alloc((size_t)128 * 256 * 2);
    float* Wh1 = (float*)alloc((size_t)NNODES * 256 * 4);
    float* as1 = (float*)alloc((size_t)NHEADS * NNODES * 4);
    float* ad1 = (float*)alloc((size_t)NHEADS * NNODES * 4);
    unsigned short* h1h = (unsigned short*)alloc((size_t)NNODES * 256 * 2);
    unsigned short* h1l = (unsigned short*)alloc((size_t)NNODES * 256 * 2);
    float* Wh2 = (float*)alloc((size_t)NNODES * 128 * 4);
    float* as2 = (float*)alloc((size_t)NHEADS * NNODES * 4);
    float* ad2 = (float*)alloc((size_t)NHEADS * NNODES * 4);

    int blocksPerCU = 0;
    hipError_t qe = hipOccupancyMaxActiveBlocksPerMultiprocessor(
        &blocksPerCU, (const void*)mega_kernel, 256, 0);
    bool coop = (qe == hipSuccess) && (blocksPerCU * 256 >= NBLK);

    if (coop) {
        void* args[] = {
            (void*)&adj, (void*)&x, (void*)&W1, (void*)&a1, (void*)&W2, (void*)&a2,
            (void*)&nbr, (void*)&deg, (void*)&B1h, (void*)&B1l, (void*)&B2h, (void*)&B2l,
            (void*)&Wh1, (void*)&as1, (void*)&ad1, (void*)&h1h, (void*)&h1l,
            (void*)&Wh2, (void*)&as2, (void*)&ad2, (void*)&outp
        };
        hipError_t le = hipLaunchCooperativeKernel((const void*)mega_kernel,
                                                   dim3(NBLK), dim3(256),
                                                   args, 0, stream);
        if (le == hipSuccess) return;
        (void)hipGetLastError();
    }

    // ---- fallback: 5-kernel path ----
    pack_b_both_kernel<<<dim3((256 * 512 + 128 * 256) / 256), dim3(256), 0, stream>>>(
        W1, W2, B1h, B1l, B2h, B2l);
    fused1_kernel<<<dim3(512 + NNODES), dim3(256), 0, stream>>>(
        adj, nbr, deg, x, B1h, B1l, a1, Wh1, as1, ad1);
    agg_kernel<64, true><<<dim3(NNODES), dim3(256), 0, stream>>>(
        Wh1, as1, ad1, nbr, deg, nullptr, h1h, h1l);
    gemm2_kernel<<<dim3(NNODES / 32, 2), dim3(256), 0, stream>>>(
        h1h, h1l, B2h, B2l, a2, Wh2, as2, ad2);
    agg_kernel<32, false><<<dim3(NNODES), dim3(256), 0, stream>>>(
        Wh2, as2, ad2, nbr, deg, outp, nullptr, nullptr);
}